// Round 7
// baseline (1266.988 us; speedup 1.0000x reference)
//
#include <hip/hip_runtime.h>
#include <hip/hip_bf16.h>
#include <stdint.h>

#define NIN    100000
#define NOUT   200000
#define KOFF   27
#define C      64
#define NPAIR  (KOFF * NIN)            // 2,700,000
#define EPS    1e-5f
#define NBUK   ((NOUT + 255) / 256)    // 782 buckets of 256 output rows
#define IPB_F  12544                   // items per block, fill
#define IPB_C  4096                    // items per block, count
#define RPB    128                     // rows per fused sub-block (half bucket)
#define TRASH  128                     // trash accumulator row for tile tails
#define ACCW   65                      // padded acc row stride (bank spread)
#define SIT    3584                    // sorted-item capacity (mean 1728, +44 sigma)
#define NTILE  256                     // tile metadata capacity

typedef __attribute__((ext_vector_type(8))) short bf16x8;
typedef __attribute__((ext_vector_type(4))) float f32x4;

// ---------------- fp32 -> bf16 conversion (8 elems / thread) ---------------
__global__ __launch_bounds__(256)
void cvt_bf16_kernel(const float* __restrict__ src, ushort* __restrict__ dst, int n8)
{
    int t = blockIdx.x * 256 + threadIdx.x;
    if (t >= n8) return;
    const float4* s4 = reinterpret_cast<const float4*>(src) + (size_t)t * 2;
    float4 a = s4[0], b = s4[1];
    float v[8] = {a.x, a.y, a.z, a.w, b.x, b.y, b.z, b.w};
    union { ushort u[8]; uint4 q; } pk;
    #pragma unroll
    for (int j = 0; j < 8; ++j) {
        __hip_bfloat16 h = __float2bfloat16(v[j]);
        pk.u[j] = *reinterpret_cast<ushort*>(&h);
    }
    reinterpret_cast<uint4*>(dst)[t] = pk.q;
}

// Transposed bf16 weight: wT[k][co][ci] = W[k][ci][co]
__global__ __launch_bounds__(256)
void cvt_wT_kernel(const float* __restrict__ w, ushort* __restrict__ wT)
{
    int t = blockIdx.x * 256 + threadIdx.x;
    if (t >= KOFF * C * C) return;
    int k   = t >> 12;
    int rem = t & 4095;
    int co  = rem >> 6, ci = rem & 63;
    __hip_bfloat16 h = __float2bfloat16(w[((size_t)k << 12) + ci * 64 + co]);
    wT[t] = *reinterpret_cast<ushort*>(&h);
}

// ---------------- Bucket binning -------------------------------------------
// bucket b = output rows [b*256, b*256+256), all 27 offsets together.
// Payload: bits[0,17)=ii  bits[17,22)=k  bits[22,30)=oi&255.

__global__ __launch_bounds__(256)
void bin_count_kernel(const int* __restrict__ out_idx, int* __restrict__ bcnt)
{
    __shared__ int hist[NBUK];
    for (int i = threadIdx.x; i < NBUK; i += 256) hist[i] = 0;
    __syncthreads();
    const int t0 = blockIdx.x * IPB_C;
    #pragma unroll 4
    for (int j = 0; j < IPB_C / 256; ++j) {
        int t = t0 + j * 256 + threadIdx.x;
        if (t < NPAIR) atomicAdd(&hist[out_idx[t] >> 8], 1);
    }
    __syncthreads();
    for (int i = threadIdx.x; i < NBUK; i += 256) {
        int c = hist[i];
        if (c) atomicAdd(&bcnt[i], c);
    }
}

__global__ __launch_bounds__(1024)
void bucket_scan_kernel(const int* __restrict__ bcnt, int* __restrict__ boff,
                        int* __restrict__ bcur)
{
    __shared__ int s[1024];
    const int t = threadIdx.x;
    int v = (t < NBUK) ? bcnt[t] : 0;
    s[t] = v;
    __syncthreads();
    for (int off = 1; off < 1024; off <<= 1) {
        int x = (t >= off) ? s[t - off] : 0;
        __syncthreads();
        s[t] += x;
        __syncthreads();
    }
    if (t < NBUK) {
        int o = s[t] - v;
        boff[t] = o;
        bcur[t] = o;
    }
    if (t == NBUK - 1) boff[NBUK] = s[t];
}

__global__ __launch_bounds__(256)
void bin_fill_kernel(const int* __restrict__ in_idx, const int* __restrict__ out_idx,
                     int* __restrict__ bcur, uint32_t* __restrict__ binned)
{
    __shared__ int hist[NBUK];
    __shared__ int base[NBUK];
    for (int i = threadIdx.x; i < NBUK; i += 256) hist[i] = 0;
    __syncthreads();
    const int t0 = blockIdx.x * IPB_F;
    for (int j = 0; j < IPB_F / 256; ++j) {
        int t = t0 + j * 256 + threadIdx.x;
        if (t < NPAIR) atomicAdd(&hist[out_idx[t] >> 8], 1);
    }
    __syncthreads();
    for (int i = threadIdx.x; i < NBUK; i += 256) {
        int c = hist[i];
        base[i] = c ? atomicAdd(&bcur[i], c) : 0;
    }
    __syncthreads();
    for (int j = 0; j < IPB_F / 256; ++j) {
        int t = t0 + j * 256 + threadIdx.x;
        if (t < NPAIR) {
            int k   = t / NIN;
            int oi  = out_idx[t];
            int ii  = in_idx[t];
            int bkt = oi >> 8;
            int p   = atomicSub(&hist[bkt], 1) - 1;
            uint32_t payload = ((uint32_t)(oi & 255) << 22)
                             | ((uint32_t)k << 17)
                             | (uint32_t)ii;
            binned[base[bkt] + p] = payload;
        }
    }
}

// ---------------- Fused conv: sort-by-k + gather-MFMA + LDS scatter --------
// Block = (bucket b, half sub): 128 output rows. Sort contributors by k,
// then per k-run tile 16 contributors through swapped MFMA and ds_add_f32
// into a padded fp32 accumulator. BN+ReLU epilogue writes out once.
__global__ __launch_bounds__(256)
void fused_conv_kernel(const ushort* __restrict__ featsb,   // [NIN][C] bf16
                       const ushort* __restrict__ wT,       // [KOFF][C][C] bf16 (co-major)
                       const uint32_t* __restrict__ binned,
                       const int* __restrict__ boff,
                       const float* __restrict__ gamma,
                       const float* __restrict__ beta,
                       const float* __restrict__ mean,
                       const float* __restrict__ var,
                       float* __restrict__ out)
{
    __shared__ float    acc[(RPB + 1) * ACCW];     // 129x65 f32, row 128 = trash
    __shared__ uint32_t sIt[SIT];
    __shared__ int khist[28], koff[28], kcur[28];
    __shared__ int tileK[NTILE], tileS[NTILE];
    __shared__ int sT;

    const int b   = blockIdx.x;
    const int sub = blockIdx.y;
    const int t   = threadIdx.x;
    const int beg = boff[b];
    const int n   = boff[b + 1] - beg;
    const int rlo = sub * RPB;

    if (t < 28) khist[t] = 0;
    for (int i = t; i < (RPB + 1) * ACCW; i += 256) acc[i] = 0.f;
    __syncthreads();

    // count by k (this half only)
    for (int i = t; i < n; i += 256) {
        uint32_t pl = binned[beg + i];
        int rl = (int)(pl >> 22) - rlo;
        if ((unsigned)rl < (unsigned)RPB) atomicAdd(&khist[(pl >> 17) & 31], 1);
    }
    __syncthreads();

    // serial scan + tile metadata (27 bins, cheap)
    if (t == 0) {
        int s = 0, ntl = 0;
        for (int k = 0; k < KOFF; ++k) {
            koff[k] = s;
            kcur[k] = s;
            int c = khist[k];
            for (int j = 0; j < c; j += 16)
                if (ntl < NTILE) { tileK[ntl] = k; tileS[ntl] = s + j; ++ntl; }
            s += c;
        }
        koff[KOFF] = s;
        sT = ntl;
    }
    __syncthreads();

    // place (counting sort by k)
    for (int i = t; i < n; i += 256) {
        uint32_t pl = binned[beg + i];
        int rl = (int)(pl >> 22) - rlo;
        if ((unsigned)rl < (unsigned)RPB) {
            int slot = atomicAdd(&kcur[(pl >> 17) & 31], 1);
            if (slot < SIT) sIt[slot] = pl;
        }
    }
    __syncthreads();

    // ---- tile processing ----
    const int T    = sT;
    const int wave = t >> 6;
    const int lane = t & 63;
    const int m16  = lane & 15;
    const int q    = lane >> 4;
    const int t0w  = (T * wave) >> 2;
    const int t1w  = (T * (wave + 1)) >> 2;

    int curk = -1;
    bf16x8 xf[4][2];
    for (int ti = t0w; ti < t1w; ++ti) {
        const int k = tileK[ti];
        if (k != curk) {
            curk = k;
            const ushort* wk = wT + ((size_t)k << 12) + (size_t)m16 * 64 + 16 * q;
            #pragma unroll
            for (int nt = 0; nt < 4; ++nt)
                #pragma unroll
                for (int kc = 0; kc < 2; ++kc)
                    xf[nt][kc] = *reinterpret_cast<const bf16x8*>(
                        wk + (size_t)nt * 1024 + kc * 32 - 8 * q);
        }
        const int kend  = koff[k + 1];
        const int idx   = tileS[ti] + m16;
        const bool valid = idx < kend;
        const uint32_t pl = sIt[valid ? idx : (kend - 1)];
        const int ii = pl & 0x1FFFF;
        const int lr = valid ? ((int)(pl >> 22) - rlo) : TRASH;

        const ushort* fr = featsb + (size_t)ii * C;
        bf16x8 y0 = *reinterpret_cast<const bf16x8*>(fr + 8 * q);
        bf16x8 y1 = *reinterpret_cast<const bf16x8*>(fr + 32 + 8 * q);

        f32x4 a0 = {0,0,0,0}, a1 = {0,0,0,0}, a2 = {0,0,0,0}, a3 = {0,0,0,0};
        a0 = __builtin_amdgcn_mfma_f32_16x16x32_bf16(xf[0][0], y0, a0, 0, 0, 0);
        a1 = __builtin_amdgcn_mfma_f32_16x16x32_bf16(xf[1][0], y0, a1, 0, 0, 0);
        a2 = __builtin_amdgcn_mfma_f32_16x16x32_bf16(xf[2][0], y0, a2, 0, 0, 0);
        a3 = __builtin_amdgcn_mfma_f32_16x16x32_bf16(xf[3][0], y0, a3, 0, 0, 0);
        a0 = __builtin_amdgcn_mfma_f32_16x16x32_bf16(xf[0][1], y1, a0, 0, 0, 0);
        a1 = __builtin_amdgcn_mfma_f32_16x16x32_bf16(xf[1][1], y1, a1, 0, 0, 0);
        a2 = __builtin_amdgcn_mfma_f32_16x16x32_bf16(xf[2][1], y1, a2, 0, 0, 0);
        a3 = __builtin_amdgcn_mfma_f32_16x16x32_bf16(xf[3][1], y1, a3, 0, 0, 0);

        float* arow = acc + lr * ACCW + 4 * q;
        f32x4 accs[4] = {a0, a1, a2, a3};
        #pragma unroll
        for (int nt = 0; nt < 4; ++nt)
            #pragma unroll
            for (int r = 0; r < 4; ++r)
                atomicAdd(&arow[nt * 16 + r], accs[nt][r]);
    }
    __syncthreads();

    // ---- BN + ReLU epilogue ----
    const int cpT = t & 15;
    float sc[4], sh[4];
    #pragma unroll
    for (int r = 0; r < 4; ++r) {
        const int c = cpT * 4 + r;
        float s = gamma[c] * rsqrtf(var[c] + EPS);
        sc[r] = s;
        sh[r] = beta[c] - mean[c] * s;
    }
    float4* out4 = reinterpret_cast<float4*>(out);
    #pragma unroll
    for (int rep = 0; rep < RPB * 16 / 256; ++rep) {   // 8 reps
        const int i   = t + rep * 256;
        const int rl  = i >> 4;
        const int row = b * 256 + rlo + rl;
        if (row < NOUT) {
            const float* ap = acc + rl * ACCW + cpT * 4;
            float v0 = fmaf(ap[0], sc[0], sh[0]); v0 = v0 > 0.f ? v0 : 0.f;
            float v1 = fmaf(ap[1], sc[1], sh[1]); v1 = v1 > 0.f ? v1 : 0.f;
            float v2 = fmaf(ap[2], sc[2], sh[2]); v2 = v2 > 0.f ? v2 : 0.f;
            float v3 = fmaf(ap[3], sc[3], sh[3]); v3 = v3 > 0.f ? v3 : 0.f;
            out4[(size_t)row * 16 + cpT] = make_float4(v0, v1, v2, v3);
        }
    }
}

// ---------------- Fallback (atomic path, tiny ws) --------------------------
__global__ __launch_bounds__(256)
void conv_scatter_kernel(const float* __restrict__ feats,
                         const float* __restrict__ weight,
                         const int*   __restrict__ in_idx,
                         const int*   __restrict__ out_idx,
                         float*       __restrict__ out)
{
    const int k    = blockIdx.y;
    const int lane = threadIdx.x & 63;
    const int wave = threadIdx.x >> 6;
    const int wavesInGrid = gridDim.x * 4;
    const int waveId      = blockIdx.x * 4 + wave;

    const float* wk = weight + (size_t)k * C * C + lane;
    float w[C];
    #pragma unroll
    for (int ci = 0; ci < C; ++ci) w[ci] = wk[(size_t)ci * C];

    const int* ii_k = in_idx  + (size_t)k * NIN;
    const int* oi_k = out_idx + (size_t)k * NIN;

    for (int r = waveId; r < NIN; r += wavesInGrid) {
        const int ii = ii_k[r];
        const int oi = oi_k[r];
        const float4* frow = reinterpret_cast<const float4*>(feats + (size_t)ii * C);
        float acc = 0.0f;
        #pragma unroll
        for (int j = 0; j < C / 4; ++j) {
            float4 f = frow[j];
            acc = fmaf(f.x, w[4 * j + 0], acc);
            acc = fmaf(f.y, w[4 * j + 1], acc);
            acc = fmaf(f.z, w[4 * j + 2], acc);
            acc = fmaf(f.w, w[4 * j + 3], acc);
        }
        atomicAdd(out + (size_t)oi * C + lane, acc);
    }
}

__global__ __launch_bounds__(256)
void bn_relu_kernel(float* __restrict__ out,
                    const float* __restrict__ gamma,
                    const float* __restrict__ beta,
                    const float* __restrict__ mean,
                    const float* __restrict__ var)
{
    const int total4 = NOUT * C / 4;
    int idx = blockIdx.x * blockDim.x + threadIdx.x;
    if (idx >= total4) return;
    const int c0 = (idx * 4) & (C - 1);
    float sc[4], sh[4];
    #pragma unroll
    for (int j = 0; j < 4; ++j) {
        const int c  = c0 + j;
        const float s = gamma[c] * rsqrtf(var[c] + EPS);
        sc[j] = s;
        sh[j] = beta[c] - mean[c] * s;
    }
    float4* p = reinterpret_cast<float4*>(out) + idx;
    float4 v = *p;
    v.x = fmaf(v.x, sc[0], sh[0]); v.x = v.x > 0.f ? v.x : 0.f;
    v.y = fmaf(v.y, sc[1], sh[1]); v.y = v.y > 0.f ? v.y : 0.f;
    v.z = fmaf(v.z, sc[2], sh[2]); v.z = v.z > 0.f ? v.z : 0.f;
    v.w = fmaf(v.w, sc[3], sh[3]); v.w = v.w > 0.f ? v.w : 0.f;
    *p = v;
}

// ---------------------------------------------------------------------------
extern "C" void kernel_launch(void* const* d_in, const int* in_sizes, int n_in,
                              void* d_out, int out_size, void* d_ws, size_t ws_size,
                              hipStream_t stream) {
    const float* feats   = (const float*)d_in[0];
    const float* weight  = (const float*)d_in[1];
    const int*   in_idx  = (const int*)  d_in[2];
    const int*   out_idx = (const int*)  d_in[3];
    const float* gamma   = (const float*)d_in[4];
    const float* beta    = (const float*)d_in[5];
    const float* rmean   = (const float*)d_in[6];
    const float* rvar    = (const float*)d_in[7];
    float* out = (float*)d_out;

    auto align = [](size_t x) { return (x + 255) & ~(size_t)255; };

    size_t a = 0;
    size_t oBin  = a; a += align((size_t)NPAIR * 4);           // binned payloads
    size_t oBcnt = a; a += align((size_t)NBUK * 4);            // bcnt
    size_t oBoff = a; a += align((size_t)(NBUK + 1) * 4);      // boff
    size_t oBcur = a; a += align((size_t)NBUK * 4);            // bcur
    size_t oFb   = a; a += align((size_t)NIN * C * 2);         // feats bf16
    size_t oWt   = a; a += align((size_t)KOFF * C * C * 2);    // weight^T bf16

    if (ws_size < a) {
        hipMemsetAsync(out, 0, (size_t)out_size * sizeof(float), stream);
        dim3 grid(512, KOFF);
        conv_scatter_kernel<<<grid, 256, 0, stream>>>(feats, weight, in_idx, out_idx, out);
        const int total4 = NOUT * C / 4;
        bn_relu_kernel<<<(total4 + 255) / 256, 256, 0, stream>>>(out, gamma, beta, rmean, rvar);
        return;
    }

    char* ws = (char*)d_ws;
    uint32_t* binned = (uint32_t*)(ws + oBin);
    int* bcnt = (int*)(ws + oBcnt);
    int* boff = (int*)(ws + oBoff);
    int* bcur = (int*)(ws + oBcur);
    ushort* featsb = (ushort*)(ws + oFb);
    ushort* wT     = (ushort*)(ws + oWt);

    // --- conversions ---
    {
        int n8f = NIN * C / 8;
        cvt_bf16_kernel<<<(n8f + 255) / 256, 256, 0, stream>>>(feats, featsb, n8f);
        int nw = KOFF * C * C;
        cvt_wT_kernel<<<(nw + 255) / 256, 256, 0, stream>>>(weight, wT);
    }

    // --- bucket binning ---
    hipMemsetAsync(bcnt, 0, (size_t)NBUK * sizeof(int), stream);
    {
        int nbC = (NPAIR + IPB_C - 1) / IPB_C;
        bin_count_kernel<<<nbC, 256, 0, stream>>>(out_idx, bcnt);
        bucket_scan_kernel<<<1, 1024, 0, stream>>>(bcnt, boff, bcur);
        int nbF = (NPAIR + IPB_F - 1) / IPB_F;
        bin_fill_kernel<<<nbF, 256, 0, stream>>>(in_idx, out_idx, bcur, binned);
    }

    // --- fused gather-MFMA-scatter + BN + ReLU ---
    {
        dim3 grid(NBUK, 2);
        fused_conv_kernel<<<grid, 256, 0, stream>>>(featsb, wT, binned, boff,
                                                    gamma, beta, rmean, rvar, out);
    }
}

// Round 8
// 329.892 us; speedup vs baseline: 3.8406x; 3.8406x over previous
//
#include <hip/hip_runtime.h>
#include <hip/hip_bf16.h>
#include <stdint.h>

#define NIN    100000
#define NOUT   200000
#define KOFF   27
#define C      64
#define NPAIR  (KOFF * NIN)            // 2,700,000
#define EPS    1e-5f
#define NBUK   ((NOUT + 255) / 256)    // 782 buckets of 256 output rows
#define MAXGB  4704                    // >= G*NBUK for kpg >= 5 (G<=6)
#define IPB_F  12544                   // items per block, fill (49*256)
#define IPB_C  4096                    // items per block, count
#define RPB    128                     // rows per gather sub-block
#define SIT    3072                    // sorted-item capacity per sub-block

typedef __attribute__((ext_vector_type(8))) short bf16x8;
typedef __attribute__((ext_vector_type(4))) float f32x4;

// ---------------- fp32 -> bf16 conversion (8 elems / thread) ---------------
__global__ __launch_bounds__(256)
void cvt_bf16_kernel(const float* __restrict__ src, ushort* __restrict__ dst, int n8)
{
    int t = blockIdx.x * 256 + threadIdx.x;
    if (t >= n8) return;
    const float4* s4 = reinterpret_cast<const float4*>(src) + (size_t)t * 2;
    float4 a = s4[0], b = s4[1];
    float v[8] = {a.x, a.y, a.z, a.w, b.x, b.y, b.z, b.w};
    union { ushort u[8]; uint4 q; } pk;
    #pragma unroll
    for (int j = 0; j < 8; ++j) {
        __hip_bfloat16 h = __float2bfloat16(v[j]);
        pk.u[j] = *reinterpret_cast<ushort*>(&h);
    }
    reinterpret_cast<uint4*>(dst)[t] = pk.q;
}

// ---------------- Phase A: MFMA GEMM  P_chunk[lk] = feats @ W[k0+lk] -------
// Wave = 16-row M-tile x 64 channels for one offset. Operand-swapped MFMA:
// lane l, reg r holds out[row = lane&15][chan = nt*16 + (lane>>4)*4 + r].
__global__ __launch_bounds__(256)
void gemm_mfma_kernel(const ushort* __restrict__ featsb,   // [NIN][C] bf16
                      const ushort* __restrict__ weightb,  // [KOFF][C][C] bf16
                      ushort* __restrict__ P,              // [kcnt][NIN][C] bf16
                      int k0)
{
    const int lk   = blockIdx.y;
    const int k    = k0 + lk;
    const int lane = threadIdx.x & 63;
    const int wave = threadIdx.x >> 6;
    const int m16  = lane & 15;
    const int q    = lane >> 4;        // 0..3

    const ushort* wb = weightb + (size_t)k * C * C;
    bf16x8 xf[4][2];
    #pragma unroll
    for (int nt = 0; nt < 4; ++nt)
        #pragma unroll
        for (int kc = 0; kc < 2; ++kc)
            #pragma unroll
            for (int j = 0; j < 8; ++j)
                xf[nt][kc][j] = (short)wb[(size_t)(kc * 32 + 8 * q + j) * C + nt * 16 + m16];

    ushort* Pk = P + (size_t)lk * NIN * C;
    const int tiles = NIN / 16;        // 6250 exactly

    for (int tile = blockIdx.x * 4 + wave; tile < tiles; tile += gridDim.x * 4) {
        const int mbase = tile * 16;
        const ushort* fr = featsb + (size_t)(mbase + m16) * C;
        bf16x8 y0 = *reinterpret_cast<const bf16x8*>(fr + 8 * q);
        bf16x8 y1 = *reinterpret_cast<const bf16x8*>(fr + 32 + 8 * q);

        f32x4 acc0 = {0,0,0,0}, acc1 = {0,0,0,0}, acc2 = {0,0,0,0}, acc3 = {0,0,0,0};
        acc0 = __builtin_amdgcn_mfma_f32_16x16x32_bf16(xf[0][0], y0, acc0, 0, 0, 0);
        acc1 = __builtin_amdgcn_mfma_f32_16x16x32_bf16(xf[1][0], y0, acc1, 0, 0, 0);
        acc2 = __builtin_amdgcn_mfma_f32_16x16x32_bf16(xf[2][0], y0, acc2, 0, 0, 0);
        acc3 = __builtin_amdgcn_mfma_f32_16x16x32_bf16(xf[3][0], y0, acc3, 0, 0, 0);
        acc0 = __builtin_amdgcn_mfma_f32_16x16x32_bf16(xf[0][1], y1, acc0, 0, 0, 0);
        acc1 = __builtin_amdgcn_mfma_f32_16x16x32_bf16(xf[1][1], y1, acc1, 0, 0, 0);
        acc2 = __builtin_amdgcn_mfma_f32_16x16x32_bf16(xf[2][1], y1, acc2, 0, 0, 0);
        acc3 = __builtin_amdgcn_mfma_f32_16x16x32_bf16(xf[3][1], y1, acc3, 0, 0, 0);

        ushort* prow = Pk + (size_t)(mbase + m16) * C;
        f32x4 accs[4] = {acc0, acc1, acc2, acc3};
        #pragma unroll
        for (int nt = 0; nt < 4; ++nt) {
            union { ushort u[4]; uint2 v; } pk;
            #pragma unroll
            for (int r = 0; r < 4; ++r) {
                __hip_bfloat16 h = __float2bfloat16(accs[nt][r]);
                pk.u[r] = *reinterpret_cast<ushort*>(&h);
            }
            *reinterpret_cast<uint2*>(prow + nt * 16 + q * 4) = pk.v;
        }
    }
}

// ---------------- Phase B: bucket binning ----------------------------------
// bucket (g,b) = pairs whose out_idx is in rows [b*256, b*256+256) for group g.
// Payload: bits[0,17)=ii  bits[17,21)=lk (group-local k)  bits[21,29)=oi&255.

__global__ __launch_bounds__(256)
void bin_count_kernel(const int* __restrict__ out_idx, int* __restrict__ bcnt,
                      int kpg, int GB)
{
    __shared__ int hist[MAXGB];
    for (int i = threadIdx.x; i < GB; i += 256) hist[i] = 0;
    __syncthreads();
    const int t0 = blockIdx.x * IPB_C;
    #pragma unroll 4
    for (int j = 0; j < IPB_C / 256; ++j) {
        int t = t0 + j * 256 + threadIdx.x;
        if (t < NPAIR) {
            int g  = (t / NIN) / kpg;
            int oi = out_idx[t];
            atomicAdd(&hist[g * NBUK + (oi >> 8)], 1);
        }
    }
    __syncthreads();
    for (int i = threadIdx.x; i < GB; i += 256) {
        int c = hist[i];
        if (c) atomicAdd(&bcnt[i], c);
    }
}

// exclusive scan of bcnt[GB] -> boff[GB+1]; bcur := boff.  One block.
__global__ __launch_bounds__(1024)
void bucket_scan_kernel(const int* __restrict__ bcnt, int* __restrict__ boff,
                        int* __restrict__ bcur, int GB)
{
    __shared__ int s[1024];
    const int t   = threadIdx.x;
    const int per = (GB + 1023) / 1024;      // <= 5
    int local[8];
    int sum = 0;
    for (int j = 0; j < per; ++j) {
        int idx = t * per + j;
        int v = (idx < GB) ? bcnt[idx] : 0;
        local[j] = sum;
        sum += v;
    }
    s[t] = sum;
    __syncthreads();
    for (int off = 1; off < 1024; off <<= 1) {
        int x = (t >= off) ? s[t - off] : 0;
        __syncthreads();
        s[t] += x;
        __syncthreads();
    }
    int tbase = (t > 0) ? s[t - 1] : 0;
    for (int j = 0; j < per; ++j) {
        int idx = t * per + j;
        if (idx < GB) {
            int o = tbase + local[j];
            boff[idx] = o;
            bcur[idx] = o;
        }
    }
    if (t == 1023) boff[GB] = s[1023];
}

// Per-block: LDS hist -> reserve global ranges -> write payloads in runs.
__global__ __launch_bounds__(256)
void bin_fill_kernel(const int* __restrict__ in_idx, const int* __restrict__ out_idx,
                     int* __restrict__ bcur, uint32_t* __restrict__ binned,
                     int kpg, int GB)
{
    __shared__ int hist[MAXGB];
    __shared__ int base[MAXGB];
    for (int i = threadIdx.x; i < GB; i += 256) hist[i] = 0;
    __syncthreads();
    const int t0 = blockIdx.x * IPB_F;
    for (int j = 0; j < IPB_F / 256; ++j) {
        int t = t0 + j * 256 + threadIdx.x;
        if (t < NPAIR) {
            int g  = (t / NIN) / kpg;
            int oi = out_idx[t];
            atomicAdd(&hist[g * NBUK + (oi >> 8)], 1);
        }
    }
    __syncthreads();
    for (int i = threadIdx.x; i < GB; i += 256) {
        int c = hist[i];
        base[i] = c ? atomicAdd(&bcur[i], c) : 0;
    }
    __syncthreads();
    for (int j = 0; j < IPB_F / 256; ++j) {
        int t = t0 + j * 256 + threadIdx.x;
        if (t < NPAIR) {
            int k   = t / NIN;
            int g   = k / kpg;
            int oi  = out_idx[t];
            int ii  = in_idx[t];
            int bkt = g * NBUK + (oi >> 8);
            int p   = atomicSub(&hist[bkt], 1) - 1;
            uint32_t payload = ((uint32_t)(oi & 255) << 21)
                             | ((uint32_t)(k - g * kpg) << 17)
                             | (uint32_t)ii;
            binned[base[bkt] + p] = payload;
        }
    }
}

// ---------------- Phase C: per-half-bucket LDS sort + gather + BN/ReLU -----
// Block = (bucket b, half sub): 128 output rows. Counting-sort the bucket's
// payloads that land in this half, then 16 threads/row reduce P rows with
// 4-deep load ILP.
__global__ __launch_bounds__(256)
void gather_bucket_kernel(const uint2* __restrict__ P2,
                          const uint32_t* __restrict__ binned,
                          const int* __restrict__ boff, int gbase,
                          const float* __restrict__ gamma,
                          const float* __restrict__ beta,
                          const float* __restrict__ mean,
                          const float* __restrict__ var,
                          float* __restrict__ out,
                          int accumulate, int finalize)
{
    __shared__ uint32_t sIt[SIT];
    __shared__ int sCnt[RPB];
    __shared__ int sOff[RPB + 1];
    __shared__ int sCur[RPB];

    const int b   = blockIdx.x;
    const int sub = blockIdx.y;                  // 0/1 -> rows [sub*128, +128)
    const int t   = threadIdx.x;
    const int beg = boff[gbase + b];
    const int n   = boff[gbase + b + 1] - beg;
    const int rlo = sub * RPB;

    if (t < RPB) sCnt[t] = 0;
    __syncthreads();
    for (int i = t; i < n; i += 256) {
        int rl = (int)(binned[beg + i] >> 21) - rlo;
        if ((unsigned)rl < (unsigned)RPB) atomicAdd(&sCnt[rl], 1);
    }
    __syncthreads();
    // inclusive scan over RPB entries (first 128 threads)
    if (t < RPB) sOff[t + 1] = sCnt[t];
    __syncthreads();
    for (int off = 1; off < RPB; off <<= 1) {
        int x = 0;
        if (t < RPB && t >= off) x = sOff[t + 1 - off];
        __syncthreads();
        if (t < RPB) sOff[t + 1] += x;
        __syncthreads();
    }
    if (t == 0) sOff[0] = 0;
    __syncthreads();
    if (t < RPB) sCur[t] = sOff[t + 1] - sCnt[t];
    __syncthreads();
    for (int i = t; i < n; i += 256) {
        uint32_t pl = binned[beg + i];
        int rl = (int)(pl >> 21) - rlo;
        if ((unsigned)rl < (unsigned)RPB) {
            int slot = atomicAdd(&sCur[rl], 1);
            if (slot < SIT) sIt[slot] = pl;
        }
    }
    __syncthreads();

    const int cp = t & 15;
    const int c0 = cp * 4;
    float sc[4], sh[4];
    if (finalize) {
        #pragma unroll
        for (int r = 0; r < 4; ++r) {
            const int c = c0 + r;
            float s = gamma[c] * rsqrtf(var[c] + EPS);
            sc[r] = s;
            sh[r] = beta[c] - mean[c] * s;
        }
    }

    float4* out4 = reinterpret_cast<float4*>(out);
    #pragma unroll 1
    for (int it = 0; it < RPB / 16; ++it) {
        const int rl  = (t >> 4) + it * 16;
        const int row = b * 256 + rlo + rl;
        if (row >= NOUT) continue;
        int j  = sOff[rl];
        const int je = sOff[rl + 1];

        float a0 = 0.f, a1 = 0.f, a2 = 0.f, a3 = 0.f;
        for (; j + 3 < je; j += 4) {              // 4 loads in flight
            uint32_t p0 = sIt[j],     p1 = sIt[j + 1];
            uint32_t p2 = sIt[j + 2], p3 = sIt[j + 3];
            uint2 u0 = P2[((size_t)((p0 >> 17) & 15) * NIN + (p0 & 0x1FFFF)) * 16 + cp];
            uint2 u1 = P2[((size_t)((p1 >> 17) & 15) * NIN + (p1 & 0x1FFFF)) * 16 + cp];
            uint2 u2 = P2[((size_t)((p2 >> 17) & 15) * NIN + (p2 & 0x1FFFF)) * 16 + cp];
            uint2 u3 = P2[((size_t)((p3 >> 17) & 15) * NIN + (p3 & 0x1FFFF)) * 16 + cp];
            a0 += __uint_as_float(u0.x << 16);
            a1 += __uint_as_float(u0.x & 0xffff0000u);
            a2 += __uint_as_float(u0.y << 16);
            a3 += __uint_as_float(u0.y & 0xffff0000u);
            a0 += __uint_as_float(u1.x << 16);
            a1 += __uint_as_float(u1.x & 0xffff0000u);
            a2 += __uint_as_float(u1.y << 16);
            a3 += __uint_as_float(u1.y & 0xffff0000u);
            a0 += __uint_as_float(u2.x << 16);
            a1 += __uint_as_float(u2.x & 0xffff0000u);
            a2 += __uint_as_float(u2.y << 16);
            a3 += __uint_as_float(u2.y & 0xffff0000u);
            a0 += __uint_as_float(u3.x << 16);
            a1 += __uint_as_float(u3.x & 0xffff0000u);
            a2 += __uint_as_float(u3.y << 16);
            a3 += __uint_as_float(u3.y & 0xffff0000u);
        }
        for (; j < je; ++j) {
            uint32_t p0 = sIt[j];
            uint2 u0 = P2[((size_t)((p0 >> 17) & 15) * NIN + (p0 & 0x1FFFF)) * 16 + cp];
            a0 += __uint_as_float(u0.x << 16);
            a1 += __uint_as_float(u0.x & 0xffff0000u);
            a2 += __uint_as_float(u0.y << 16);
            a3 += __uint_as_float(u0.y & 0xffff0000u);
        }

        const size_t oidx = (size_t)row * 16 + cp;
        if (accumulate) {
            float4 pv = out4[oidx];
            a0 += pv.x; a1 += pv.y; a2 += pv.z; a3 += pv.w;
        }
        if (finalize) {
            a0 = fmaf(a0, sc[0], sh[0]); a0 = a0 > 0.f ? a0 : 0.f;
            a1 = fmaf(a1, sc[1], sh[1]); a1 = a1 > 0.f ? a1 : 0.f;
            a2 = fmaf(a2, sc[2], sh[2]); a2 = a2 > 0.f ? a2 : 0.f;
            a3 = fmaf(a3, sc[3], sh[3]); a3 = a3 > 0.f ? a3 : 0.f;
        }
        out4[oidx] = make_float4(a0, a1, a2, a3);
    }
}

// ---------------- Fallback (atomic path, tiny ws) --------------------------
__global__ __launch_bounds__(256)
void conv_scatter_kernel(const float* __restrict__ feats,
                         const float* __restrict__ weight,
                         const int*   __restrict__ in_idx,
                         const int*   __restrict__ out_idx,
                         float*       __restrict__ out)
{
    const int k    = blockIdx.y;
    const int lane = threadIdx.x & 63;
    const int wave = threadIdx.x >> 6;
    const int wavesInGrid = gridDim.x * 4;
    const int waveId      = blockIdx.x * 4 + wave;

    const float* wk = weight + (size_t)k * C * C + lane;
    float w[C];
    #pragma unroll
    for (int ci = 0; ci < C; ++ci) w[ci] = wk[(size_t)ci * C];

    const int* ii_k = in_idx  + (size_t)k * NIN;
    const int* oi_k = out_idx + (size_t)k * NIN;

    for (int r = waveId; r < NIN; r += wavesInGrid) {
        const int ii = ii_k[r];
        const int oi = oi_k[r];
        const float4* frow = reinterpret_cast<const float4*>(feats + (size_t)ii * C);
        float acc = 0.0f;
        #pragma unroll
        for (int j = 0; j < C / 4; ++j) {
            float4 f = frow[j];
            acc = fmaf(f.x, w[4 * j + 0], acc);
            acc = fmaf(f.y, w[4 * j + 1], acc);
            acc = fmaf(f.z, w[4 * j + 2], acc);
            acc = fmaf(f.w, w[4 * j + 3], acc);
        }
        atomicAdd(out + (size_t)oi * C + lane, acc);
    }
}

__global__ __launch_bounds__(256)
void bn_relu_kernel(float* __restrict__ out,
                    const float* __restrict__ gamma,
                    const float* __restrict__ beta,
                    const float* __restrict__ mean,
                    const float* __restrict__ var)
{
    const int total4 = NOUT * C / 4;
    int idx = blockIdx.x * blockDim.x + threadIdx.x;
    if (idx >= total4) return;
    const int c0 = (idx * 4) & (C - 1);
    float sc[4], sh[4];
    #pragma unroll
    for (int j = 0; j < 4; ++j) {
        const int c  = c0 + j;
        const float s = gamma[c] * rsqrtf(var[c] + EPS);
        sc[j] = s;
        sh[j] = beta[c] - mean[c] * s;
    }
    float4* p = reinterpret_cast<float4*>(out) + idx;
    float4 v = *p;
    v.x = fmaf(v.x, sc[0], sh[0]); v.x = v.x > 0.f ? v.x : 0.f;
    v.y = fmaf(v.y, sc[1], sh[1]); v.y = v.y > 0.f ? v.y : 0.f;
    v.z = fmaf(v.z, sc[2], sh[2]); v.z = v.z > 0.f ? v.z : 0.f;
    v.w = fmaf(v.w, sc[3], sh[3]); v.w = v.w > 0.f ? v.w : 0.f;
    *p = v;
}

// ---------------------------------------------------------------------------
extern "C" void kernel_launch(void* const* d_in, const int* in_sizes, int n_in,
                              void* d_out, int out_size, void* d_ws, size_t ws_size,
                              hipStream_t stream) {
    const float* feats   = (const float*)d_in[0];
    const float* weight  = (const float*)d_in[1];
    const int*   in_idx  = (const int*)  d_in[2];
    const int*   out_idx = (const int*)  d_in[3];
    const float* gamma   = (const float*)d_in[4];
    const float* beta    = (const float*)d_in[5];
    const float* rmean   = (const float*)d_in[6];
    const float* rvar    = (const float*)d_in[7];
    float* out = (float*)d_out;

    auto align = [](size_t x) { return (x + 255) & ~(size_t)255; };

    // Pick largest kpg <= 7 whose buffers fit. kpg=7 (G=4) keeps the P chunk
    // at 89.6 MB so the per-group working set (P + out + feats + binned
    // ~ 165 MB) stays Infinity-Cache-resident: P round-trips through L3
    // instead of HBM (round-6 @ kpg=14 showed 200 MB HBM writes per group).
    int kpg = 0, G = 0;
    size_t oBin = 0, oBcnt = 0, oBoff = 0, oBcur = 0, oFb = 0, oWb = 0, oP = 0;
    for (int t = 7; t >= 1; --t) {
        int g  = (KOFF + t - 1) / t;
        int gb = g * NBUK;
        if (gb > MAXGB) break;
        size_t a = 0;
        size_t bi = a; a += align((size_t)NPAIR * 4);             // binned payloads
        size_t bc = a; a += align((size_t)gb * 4);                // bcnt
        size_t bo = a; a += align((size_t)(gb + 1) * 4);          // boff
        size_t bu = a; a += align((size_t)gb * 4);                // bcur
        size_t fb = a; a += align((size_t)NIN * C * 2);           // feats bf16
        size_t wb = a; a += align((size_t)KOFF * C * C * 2);      // weight bf16
        size_t q_ = a; a += align((size_t)t * NIN * C * 2);       // P_chunk bf16
        if (a <= ws_size) {
            kpg = t; G = g;
            oBin = bi; oBcnt = bc; oBoff = bo; oBcur = bu; oFb = fb; oWb = wb; oP = q_;
            break;
        }
    }

    if (kpg == 0) {
        hipMemsetAsync(out, 0, (size_t)out_size * sizeof(float), stream);
        dim3 grid(512, KOFF);
        conv_scatter_kernel<<<grid, 256, 0, stream>>>(feats, weight, in_idx, out_idx, out);
        const int total4 = NOUT * C / 4;
        bn_relu_kernel<<<(total4 + 255) / 256, 256, 0, stream>>>(out, gamma, beta, rmean, rvar);
        return;
    }

    const int GB = G * NBUK;
    char* ws = (char*)d_ws;
    uint32_t* binned = (uint32_t*)(ws + oBin);
    int* bcnt = (int*)(ws + oBcnt);
    int* boff = (int*)(ws + oBoff);
    int* bcur = (int*)(ws + oBcur);
    ushort* featsb  = (ushort*)(ws + oFb);
    ushort* weightb = (ushort*)(ws + oWb);
    ushort* P       = (ushort*)(ws + oP);

    // --- bf16 conversions ---
    {
        int n8f = NIN * C / 8;
        cvt_bf16_kernel<<<(n8f + 255) / 256, 256, 0, stream>>>(feats, featsb, n8f);
        int n8w = KOFF * C * C / 8;
        cvt_bf16_kernel<<<(n8w + 255) / 256, 256, 0, stream>>>(weight, weightb, n8w);
    }

    // --- Bucket binning ---
    hipMemsetAsync(bcnt, 0, (size_t)GB * sizeof(int), stream);
    {
        int nbC = (NPAIR + IPB_C - 1) / IPB_C;
        bin_count_kernel<<<nbC, 256, 0, stream>>>(out_idx, bcnt, kpg, GB);
        bucket_scan_kernel<<<1, 1024, 0, stream>>>(bcnt, boff, bcur, GB);
        int nbF = (NPAIR + IPB_F - 1) / IPB_F;
        bin_fill_kernel<<<nbF, 256, 0, stream>>>(in_idx, out_idx, bcur, binned, kpg, GB);
    }

    // --- Per-group: MFMA GEMM chunk, then half-bucket gather into out ---
    for (int g = 0; g < G; ++g) {
        const int k0   = g * kpg;
        const int kcnt = (k0 + kpg <= KOFF) ? kpg : (KOFF - k0);

        dim3 grid(128, kcnt);
        gemm_mfma_kernel<<<grid, 256, 0, stream>>>(featsb, weightb, P, k0);

        dim3 ggrid(NBUK, 2);
        gather_bucket_kernel<<<ggrid, 256, 0, stream>>>(
            (const uint2*)P, binned, boff, g * NBUK,
            gamma, beta, rmean, rvar, out,
            /*accumulate=*/(g > 0), /*finalize=*/(g == G - 1));
    }
}

// Round 9
// 317.412 us; speedup vs baseline: 3.9916x; 1.0393x over previous
//
#include <hip/hip_runtime.h>
#include <hip/hip_bf16.h>
#include <stdint.h>

#define NIN    100000
#define NOUT   200000
#define KOFF   27
#define C      64
#define NPAIR  (KOFF * NIN)            // 2,700,000
#define EPS    1e-5f
#define NBUK   ((NOUT + 255) / 256)    // 782 buckets of 256 output rows
#define IPB_F  12544                   // items per block, fill (49*256)
#define IPB_C  4096                    // items per block, count
#define RPB    128                     // rows per gather sub-block
#define SIT    3072                    // sorted-item capacity per sub-block

typedef __attribute__((ext_vector_type(8))) short bf16x8;
typedef __attribute__((ext_vector_type(4))) float f32x4;

// ---------------- fp32 -> bf16 conversion (8 elems / thread) ---------------
__global__ __launch_bounds__(256)
void cvt_bf16_kernel(const float* __restrict__ src, ushort* __restrict__ dst, int n8)
{
    int t = blockIdx.x * 256 + threadIdx.x;
    if (t >= n8) return;
    const float4* s4 = reinterpret_cast<const float4*>(src) + (size_t)t * 2;
    float4 a = s4[0], b = s4[1];
    float v[8] = {a.x, a.y, a.z, a.w, b.x, b.y, b.z, b.w};
    union { ushort u[8]; uint4 q; } pk;
    #pragma unroll
    for (int j = 0; j < 8; ++j) {
        __hip_bfloat16 h = __float2bfloat16(v[j]);
        pk.u[j] = *reinterpret_cast<ushort*>(&h);
    }
    reinterpret_cast<uint4*>(dst)[t] = pk.q;
}

// ---------------- Phase A: MFMA GEMM  P_chunk[lk] = feats @ W[k0+lk] -------
// Wave = 16-row M-tile x 64 channels for one offset. Operand-swapped MFMA:
// lane l, reg r holds out[row = lane&15][chan = nt*16 + (lane>>4)*4 + r].
__global__ __launch_bounds__(256)
void gemm_mfma_kernel(const ushort* __restrict__ featsb,   // [NIN][C] bf16
                      const ushort* __restrict__ weightb,  // [KOFF][C][C] bf16
                      ushort* __restrict__ P,              // [kcnt][NIN][C] bf16
                      int k0)
{
    const int lk   = blockIdx.y;
    const int k    = k0 + lk;
    const int lane = threadIdx.x & 63;
    const int wave = threadIdx.x >> 6;
    const int m16  = lane & 15;
    const int q    = lane >> 4;        // 0..3

    const ushort* wb = weightb + (size_t)k * C * C;
    bf16x8 xf[4][2];
    #pragma unroll
    for (int nt = 0; nt < 4; ++nt)
        #pragma unroll
        for (int kc = 0; kc < 2; ++kc)
            #pragma unroll
            for (int j = 0; j < 8; ++j)
                xf[nt][kc][j] = (short)wb[(size_t)(kc * 32 + 8 * q + j) * C + nt * 16 + m16];

    ushort* Pk = P + (size_t)lk * NIN * C;
    const int tiles = NIN / 16;        // 6250 exactly

    for (int tile = blockIdx.x * 4 + wave; tile < tiles; tile += gridDim.x * 4) {
        const int mbase = tile * 16;
        const ushort* fr = featsb + (size_t)(mbase + m16) * C;
        bf16x8 y0 = *reinterpret_cast<const bf16x8*>(fr + 8 * q);
        bf16x8 y1 = *reinterpret_cast<const bf16x8*>(fr + 32 + 8 * q);

        f32x4 acc0 = {0,0,0,0}, acc1 = {0,0,0,0}, acc2 = {0,0,0,0}, acc3 = {0,0,0,0};
        acc0 = __builtin_amdgcn_mfma_f32_16x16x32_bf16(xf[0][0], y0, acc0, 0, 0, 0);
        acc1 = __builtin_amdgcn_mfma_f32_16x16x32_bf16(xf[1][0], y0, acc1, 0, 0, 0);
        acc2 = __builtin_amdgcn_mfma_f32_16x16x32_bf16(xf[2][0], y0, acc2, 0, 0, 0);
        acc3 = __builtin_amdgcn_mfma_f32_16x16x32_bf16(xf[3][0], y0, acc3, 0, 0, 0);
        acc0 = __builtin_amdgcn_mfma_f32_16x16x32_bf16(xf[0][1], y1, acc0, 0, 0, 0);
        acc1 = __builtin_amdgcn_mfma_f32_16x16x32_bf16(xf[1][1], y1, acc1, 0, 0, 0);
        acc2 = __builtin_amdgcn_mfma_f32_16x16x32_bf16(xf[2][1], y1, acc2, 0, 0, 0);
        acc3 = __builtin_amdgcn_mfma_f32_16x16x32_bf16(xf[3][1], y1, acc3, 0, 0, 0);

        ushort* prow = Pk + (size_t)(mbase + m16) * C;
        f32x4 accs[4] = {acc0, acc1, acc2, acc3};
        #pragma unroll
        for (int nt = 0; nt < 4; ++nt) {
            union { ushort u[4]; uint2 v; } pk;
            #pragma unroll
            for (int r = 0; r < 4; ++r) {
                __hip_bfloat16 h = __float2bfloat16(accs[nt][r]);
                pk.u[r] = *reinterpret_cast<ushort*>(&h);
            }
            *reinterpret_cast<uint2*>(prow + nt * 16 + q * 4) = pk.v;
        }
    }
}

// ---------------- Phase B: bucket binning (per-group grids) ----------------
// bucket (g,b) = pairs whose out_idx is in rows [b*256, b*256+256) for group g.
// Payload: bits[0,17)=ii  bits[17,21)=lk (group-local k)  bits[21,29)=oi&255.
// Groups are contiguous in t, so blockIdx.y = g and each block only needs an
// NBUK-sized LDS histogram (was MAXGB=4704 -> 37KB -> 7.9% occupancy).

__global__ __launch_bounds__(256)
void bin_count_kernel(const int* __restrict__ out_idx, int* __restrict__ bcnt,
                      int kpg)
{
    __shared__ int hist[NBUK];
    const int g    = blockIdx.y;
    const int tbeg = g * kpg * NIN;
    int tend = (g + 1) * kpg * NIN;
    if (tend > NPAIR) tend = NPAIR;

    for (int i = threadIdx.x; i < NBUK; i += 256) hist[i] = 0;
    __syncthreads();
    const int t0 = tbeg + blockIdx.x * IPB_C;
    #pragma unroll 4
    for (int j = 0; j < IPB_C / 256; ++j) {
        int t = t0 + j * 256 + threadIdx.x;
        if (t < tend) atomicAdd(&hist[out_idx[t] >> 8], 1);
    }
    __syncthreads();
    int* bc = bcnt + (size_t)g * NBUK;
    for (int i = threadIdx.x; i < NBUK; i += 256) {
        int c = hist[i];
        if (c) atomicAdd(&bc[i], c);
    }
}

// exclusive scan of bcnt[GB] -> boff[GB+1]; bcur := boff.  One block.
__global__ __launch_bounds__(1024)
void bucket_scan_kernel(const int* __restrict__ bcnt, int* __restrict__ boff,
                        int* __restrict__ bcur, int GB)
{
    __shared__ int s[1024];
    const int t   = threadIdx.x;
    const int per = (GB + 1023) / 1024;      // <= 5
    int local[8];
    int sum = 0;
    for (int j = 0; j < per; ++j) {
        int idx = t * per + j;
        int v = (idx < GB) ? bcnt[idx] : 0;
        local[j] = sum;
        sum += v;
    }
    s[t] = sum;
    __syncthreads();
    for (int off = 1; off < 1024; off <<= 1) {
        int x = (t >= off) ? s[t - off] : 0;
        __syncthreads();
        s[t] += x;
        __syncthreads();
    }
    int tbase = (t > 0) ? s[t - 1] : 0;
    for (int j = 0; j < per; ++j) {
        int idx = t * per + j;
        if (idx < GB) {
            int o = tbase + local[j];
            boff[idx] = o;
            bcur[idx] = o;
        }
    }
    if (t == 1023) boff[GB] = s[1023];
}

// Per-block: LDS hist -> reserve global ranges -> write payloads in runs.
__global__ __launch_bounds__(256)
void bin_fill_kernel(const int* __restrict__ in_idx, const int* __restrict__ out_idx,
                     int* __restrict__ bcur, uint32_t* __restrict__ binned,
                     int kpg)
{
    __shared__ int hist[NBUK];
    __shared__ int base[NBUK];
    const int g    = blockIdx.y;
    const int kbeg = g * kpg;
    const int tbeg = kbeg * NIN;
    int tend = (g + 1) * kpg * NIN;
    if (tend > NPAIR) tend = NPAIR;

    for (int i = threadIdx.x; i < NBUK; i += 256) hist[i] = 0;
    __syncthreads();
    const int t0 = tbeg + blockIdx.x * IPB_F;
    for (int j = 0; j < IPB_F / 256; ++j) {
        int t = t0 + j * 256 + threadIdx.x;
        if (t < tend) atomicAdd(&hist[out_idx[t] >> 8], 1);
    }
    __syncthreads();
    int* bu = bcur + (size_t)g * NBUK;
    for (int i = threadIdx.x; i < NBUK; i += 256) {
        int c = hist[i];
        base[i] = c ? atomicAdd(&bu[i], c) : 0;
    }
    __syncthreads();
    for (int j = 0; j < IPB_F / 256; ++j) {
        int t = t0 + j * 256 + threadIdx.x;
        if (t < tend) {
            int k   = t / NIN;
            int oi  = out_idx[t];
            int ii  = in_idx[t];
            int bkt = oi >> 8;
            int p   = atomicSub(&hist[bkt], 1) - 1;
            uint32_t payload = ((uint32_t)(oi & 255) << 21)
                             | ((uint32_t)(k - kbeg) << 17)
                             | (uint32_t)ii;
            binned[base[bkt] + p] = payload;
        }
    }
}

// ---------------- Phase C: per-half-bucket LDS sort + gather + BN/ReLU -----
// Block = (bucket b, half sub): 128 output rows. Counting-sort the bucket's
// payloads that land in this half, then 16 threads/row reduce P rows with
// 4-deep load ILP.
__global__ __launch_bounds__(256)
void gather_bucket_kernel(const uint2* __restrict__ P2,
                          const uint32_t* __restrict__ binned,
                          const int* __restrict__ boff, int gbase,
                          const float* __restrict__ gamma,
                          const float* __restrict__ beta,
                          const float* __restrict__ mean,
                          const float* __restrict__ var,
                          float* __restrict__ out,
                          int accumulate, int finalize)
{
    __shared__ uint32_t sIt[SIT];
    __shared__ int sCnt[RPB];
    __shared__ int sOff[RPB + 1];
    __shared__ int sCur[RPB];

    const int b   = blockIdx.x;
    const int sub = blockIdx.y;                  // 0/1 -> rows [sub*128, +128)
    const int t   = threadIdx.x;
    const int beg = boff[gbase + b];
    const int n   = boff[gbase + b + 1] - beg;
    const int rlo = sub * RPB;

    if (t < RPB) sCnt[t] = 0;
    __syncthreads();
    for (int i = t; i < n; i += 256) {
        int rl = (int)(binned[beg + i] >> 21) - rlo;
        if ((unsigned)rl < (unsigned)RPB) atomicAdd(&sCnt[rl], 1);
    }
    __syncthreads();
    // inclusive scan over RPB entries (first 128 threads)
    if (t < RPB) sOff[t + 1] = sCnt[t];
    __syncthreads();
    for (int off = 1; off < RPB; off <<= 1) {
        int x = 0;
        if (t < RPB && t >= off) x = sOff[t + 1 - off];
        __syncthreads();
        if (t < RPB) sOff[t + 1] += x;
        __syncthreads();
    }
    if (t == 0) sOff[0] = 0;
    __syncthreads();
    if (t < RPB) sCur[t] = sOff[t + 1] - sCnt[t];
    __syncthreads();
    for (int i = t; i < n; i += 256) {
        uint32_t pl = binned[beg + i];
        int rl = (int)(pl >> 21) - rlo;
        if ((unsigned)rl < (unsigned)RPB) {
            int slot = atomicAdd(&sCur[rl], 1);
            if (slot < SIT) sIt[slot] = pl;
        }
    }
    __syncthreads();

    const int cp = t & 15;
    const int c0 = cp * 4;
    float sc[4], sh[4];
    if (finalize) {
        #pragma unroll
        for (int r = 0; r < 4; ++r) {
            const int c = c0 + r;
            float s = gamma[c] * rsqrtf(var[c] + EPS);
            sc[r] = s;
            sh[r] = beta[c] - mean[c] * s;
        }
    }

    float4* out4 = reinterpret_cast<float4*>(out);
    #pragma unroll 1
    for (int it = 0; it < RPB / 16; ++it) {
        const int rl  = (t >> 4) + it * 16;
        const int row = b * 256 + rlo + rl;
        if (row >= NOUT) continue;
        int j  = sOff[rl];
        const int je = sOff[rl + 1];

        float a0 = 0.f, a1 = 0.f, a2 = 0.f, a3 = 0.f;
        for (; j + 3 < je; j += 4) {              // 4 loads in flight
            uint32_t p0 = sIt[j],     p1 = sIt[j + 1];
            uint32_t p2 = sIt[j + 2], p3 = sIt[j + 3];
            uint2 u0 = P2[((size_t)((p0 >> 17) & 15) * NIN + (p0 & 0x1FFFF)) * 16 + cp];
            uint2 u1 = P2[((size_t)((p1 >> 17) & 15) * NIN + (p1 & 0x1FFFF)) * 16 + cp];
            uint2 u2 = P2[((size_t)((p2 >> 17) & 15) * NIN + (p2 & 0x1FFFF)) * 16 + cp];
            uint2 u3 = P2[((size_t)((p3 >> 17) & 15) * NIN + (p3 & 0x1FFFF)) * 16 + cp];
            a0 += __uint_as_float(u0.x << 16);
            a1 += __uint_as_float(u0.x & 0xffff0000u);
            a2 += __uint_as_float(u0.y << 16);
            a3 += __uint_as_float(u0.y & 0xffff0000u);
            a0 += __uint_as_float(u1.x << 16);
            a1 += __uint_as_float(u1.x & 0xffff0000u);
            a2 += __uint_as_float(u1.y << 16);
            a3 += __uint_as_float(u1.y & 0xffff0000u);
            a0 += __uint_as_float(u2.x << 16);
            a1 += __uint_as_float(u2.x & 0xffff0000u);
            a2 += __uint_as_float(u2.y << 16);
            a3 += __uint_as_float(u2.y & 0xffff0000u);
            a0 += __uint_as_float(u3.x << 16);
            a1 += __uint_as_float(u3.x & 0xffff0000u);
            a2 += __uint_as_float(u3.y << 16);
            a3 += __uint_as_float(u3.y & 0xffff0000u);
        }
        for (; j < je; ++j) {
            uint32_t p0 = sIt[j];
            uint2 u0 = P2[((size_t)((p0 >> 17) & 15) * NIN + (p0 & 0x1FFFF)) * 16 + cp];
            a0 += __uint_as_float(u0.x << 16);
            a1 += __uint_as_float(u0.x & 0xffff0000u);
            a2 += __uint_as_float(u0.y << 16);
            a3 += __uint_as_float(u0.y & 0xffff0000u);
        }

        const size_t oidx = (size_t)row * 16 + cp;
        if (accumulate) {
            float4 pv = out4[oidx];
            a0 += pv.x; a1 += pv.y; a2 += pv.z; a3 += pv.w;
        }
        if (finalize) {
            a0 = fmaf(a0, sc[0], sh[0]); a0 = a0 > 0.f ? a0 : 0.f;
            a1 = fmaf(a1, sc[1], sh[1]); a1 = a1 > 0.f ? a1 : 0.f;
            a2 = fmaf(a2, sc[2], sh[2]); a2 = a2 > 0.f ? a2 : 0.f;
            a3 = fmaf(a3, sc[3], sh[3]); a3 = a3 > 0.f ? a3 : 0.f;
        }
        out4[oidx] = make_float4(a0, a1, a2, a3);
    }
}

// ---------------- Fallback (atomic path, tiny ws) --------------------------
__global__ __launch_bounds__(256)
void conv_scatter_kernel(const float* __restrict__ feats,
                         const float* __restrict__ weight,
                         const int*   __restrict__ in_idx,
                         const int*   __restrict__ out_idx,
                         float*       __restrict__ out)
{
    const int k    = blockIdx.y;
    const int lane = threadIdx.x & 63;
    const int wave = threadIdx.x >> 6;
    const int wavesInGrid = gridDim.x * 4;
    const int waveId      = blockIdx.x * 4 + wave;

    const float* wk = weight + (size_t)k * C * C + lane;
    float w[C];
    #pragma unroll
    for (int ci = 0; ci < C; ++ci) w[ci] = wk[(size_t)ci * C];

    const int* ii_k = in_idx  + (size_t)k * NIN;
    const int* oi_k = out_idx + (size_t)k * NIN;

    for (int r = waveId; r < NIN; r += wavesInGrid) {
        const int ii = ii_k[r];
        const int oi = oi_k[r];
        const float4* frow = reinterpret_cast<const float4*>(feats + (size_t)ii * C);
        float acc = 0.0f;
        #pragma unroll
        for (int j = 0; j < C / 4; ++j) {
            float4 f = frow[j];
            acc = fmaf(f.x, w[4 * j + 0], acc);
            acc = fmaf(f.y, w[4 * j + 1], acc);
            acc = fmaf(f.z, w[4 * j + 2], acc);
            acc = fmaf(f.w, w[4 * j + 3], acc);
        }
        atomicAdd(out + (size_t)oi * C + lane, acc);
    }
}

__global__ __launch_bounds__(256)
void bn_relu_kernel(float* __restrict__ out,
                    const float* __restrict__ gamma,
                    const float* __restrict__ beta,
                    const float* __restrict__ mean,
                    const float* __restrict__ var)
{
    const int total4 = NOUT * C / 4;
    int idx = blockIdx.x * blockDim.x + threadIdx.x;
    if (idx >= total4) return;
    const int c0 = (idx * 4) & (C - 1);
    float sc[4], sh[4];
    #pragma unroll
    for (int j = 0; j < 4; ++j) {
        const int c  = c0 + j;
        const float s = gamma[c] * rsqrtf(var[c] + EPS);
        sc[j] = s;
        sh[j] = beta[c] - mean[c] * s;
    }
    float4* p = reinterpret_cast<float4*>(out) + idx;
    float4 v = *p;
    v.x = fmaf(v.x, sc[0], sh[0]); v.x = v.x > 0.f ? v.x : 0.f;
    v.y = fmaf(v.y, sc[1], sh[1]); v.y = v.y > 0.f ? v.y : 0.f;
    v.z = fmaf(v.z, sc[2], sh[2]); v.z = v.z > 0.f ? v.z : 0.f;
    v.w = fmaf(v.w, sc[3], sh[3]); v.w = v.w > 0.f ? v.w : 0.f;
    *p = v;
}

// ---------------------------------------------------------------------------
extern "C" void kernel_launch(void* const* d_in, const int* in_sizes, int n_in,
                              void* d_out, int out_size, void* d_ws, size_t ws_size,
                              hipStream_t stream) {
    const float* feats   = (const float*)d_in[0];
    const float* weight  = (const float*)d_in[1];
    const int*   in_idx  = (const int*)  d_in[2];
    const int*   out_idx = (const int*)  d_in[3];
    const float* gamma   = (const float*)d_in[4];
    const float* beta    = (const float*)d_in[5];
    const float* rmean   = (const float*)d_in[6];
    const float* rvar    = (const float*)d_in[7];
    float* out = (float*)d_out;

    auto align = [](size_t x) { return (x + 255) & ~(size_t)255; };

    // kpg=9 (G=3) balances measured effects: P chunk 115 MB keeps the gemm's
    // L3-resident write/read rate (~3.6 us/slice at kpg=7) while paying one
    // fewer out-RMW gather pass than G=4. Fall back to smaller kpg if ws
    // is tight.
    int kpg = 0, G = 0;
    size_t oBin = 0, oBcnt = 0, oBoff = 0, oBcur = 0, oFb = 0, oWb = 0, oP = 0;
    for (int t = 9; t >= 1; --t) {
        int g  = (KOFF + t - 1) / t;
        int gb = g * NBUK;
        size_t a = 0;
        size_t bi = a; a += align((size_t)NPAIR * 4);             // binned payloads
        size_t bc = a; a += align((size_t)gb * 4);                // bcnt
        size_t bo = a; a += align((size_t)(gb + 1) * 4);          // boff
        size_t bu = a; a += align((size_t)gb * 4);                // bcur
        size_t fb = a; a += align((size_t)NIN * C * 2);           // feats bf16
        size_t wb = a; a += align((size_t)KOFF * C * C * 2);      // weight bf16
        size_t q_ = a; a += align((size_t)t * NIN * C * 2);       // P_chunk bf16
        if (a <= ws_size) {
            kpg = t; G = g;
            oBin = bi; oBcnt = bc; oBoff = bo; oBcur = bu; oFb = fb; oWb = wb; oP = q_;
            break;
        }
    }

    if (kpg == 0) {
        hipMemsetAsync(out, 0, (size_t)out_size * sizeof(float), stream);
        dim3 grid(512, KOFF);
        conv_scatter_kernel<<<grid, 256, 0, stream>>>(feats, weight, in_idx, out_idx, out);
        const int total4 = NOUT * C / 4;
        bn_relu_kernel<<<(total4 + 255) / 256, 256, 0, stream>>>(out, gamma, beta, rmean, rvar);
        return;
    }

    const int GB = G * NBUK;
    char* ws = (char*)d_ws;
    uint32_t* binned = (uint32_t*)(ws + oBin);
    int* bcnt = (int*)(ws + oBcnt);
    int* boff = (int*)(ws + oBoff);
    int* bcur = (int*)(ws + oBcur);
    ushort* featsb  = (ushort*)(ws + oFb);
    ushort* weightb = (ushort*)(ws + oWb);
    ushort* P       = (ushort*)(ws + oP);

    // --- bf16 conversions ---
    {
        int n8f = NIN * C / 8;
        cvt_bf16_kernel<<<(n8f + 255) / 256, 256, 0, stream>>>(feats, featsb, n8f);
        int n8w = KOFF * C * C / 8;
        cvt_bf16_kernel<<<(n8w + 255) / 256, 256, 0, stream>>>(weight, weightb, n8w);
    }

    // --- Bucket binning (per-group grids, NBUK-sized LDS hist) ---
    hipMemsetAsync(bcnt, 0, (size_t)GB * sizeof(int), stream);
    {
        int itemsPerGroup = kpg * NIN;
        int nbC = (itemsPerGroup + IPB_C - 1) / IPB_C;
        dim3 gC(nbC, G);
        bin_count_kernel<<<gC, 256, 0, stream>>>(out_idx, bcnt, kpg);
        bucket_scan_kernel<<<1, 1024, 0, stream>>>(bcnt, boff, bcur, GB);
        int nbF = (itemsPerGroup + IPB_F - 1) / IPB_F;
        dim3 gF(nbF, G);
        bin_fill_kernel<<<gF, 256, 0, stream>>>(in_idx, out_idx, bcur, binned, kpg);
    }

    // --- Per-group: MFMA GEMM chunk, then half-bucket gather into out ---
    for (int g = 0; g < G; ++g) {
        const int k0   = g * kpg;
        const int kcnt = (k0 + kpg <= KOFF) ? kpg : (KOFF - k0);

        dim3 grid(128, kcnt);
        gemm_mfma_kernel<<<grid, 256, 0, stream>>>(featsb, weightb, P, k0);

        dim3 ggrid(NBUK, 2);
        gather_bucket_kernel<<<ggrid, 256, 0, stream>>>(
            (const uint2*)P, binned, boff, g * NBUK,
            gamma, beta, rmean, rvar, out,
            /*accumulate=*/(g > 0), /*finalize=*/(g == G - 1));
    }
}

// Round 10
// 296.213 us; speedup vs baseline: 4.2773x; 1.0716x over previous
//
#include <hip/hip_runtime.h>
#include <hip/hip_bf16.h>
#include <stdint.h>

#define NIN    100000
#define NOUT   200000
#define KOFF   27
#define C      64
#define NPAIR  (KOFF * NIN)            // 2,700,000
#define EPS    1e-5f
#define NBUK   ((NOUT + 255) / 256)    // 782 buckets of 256 output rows
#define IPB_F  4096                    // items per block, fill
#define CAP    1536                    // per-(group,bucket) segment capacity
#define RPB    128                     // rows per gather sub-block
#define SIT    3072                    // sorted-item capacity per sub-block

typedef __attribute__((ext_vector_type(8))) short bf16x8;
typedef __attribute__((ext_vector_type(4))) float f32x4;

// ---------------- fp32 -> bf16 conversion (8 elems / thread) ---------------
__global__ __launch_bounds__(256)
void cvt_bf16_kernel(const float* __restrict__ src, ushort* __restrict__ dst, int n8)
{
    int t = blockIdx.x * 256 + threadIdx.x;
    if (t >= n8) return;
    const float4* s4 = reinterpret_cast<const float4*>(src) + (size_t)t * 2;
    float4 a = s4[0], b = s4[1];
    float v[8] = {a.x, a.y, a.z, a.w, b.x, b.y, b.z, b.w};
    union { ushort u[8]; uint4 q; } pk;
    #pragma unroll
    for (int j = 0; j < 8; ++j) {
        __hip_bfloat16 h = __float2bfloat16(v[j]);
        pk.u[j] = *reinterpret_cast<ushort*>(&h);
    }
    reinterpret_cast<uint4*>(dst)[t] = pk.q;
}

// ---------------- Phase A: MFMA GEMM  P_chunk[lk] = feats @ W[k0+lk] -------
// Wave = 16-row M-tile x 64 channels for one offset. Operand-swapped MFMA:
// lane l, reg r holds out[row = lane&15][chan = nt*16 + (lane>>4)*4 + r].
__global__ __launch_bounds__(256)
void gemm_mfma_kernel(const ushort* __restrict__ featsb,   // [NIN][C] bf16
                      const ushort* __restrict__ weightb,  // [KOFF][C][C] bf16
                      ushort* __restrict__ P,              // [kcnt][NIN][C] bf16
                      int k0)
{
    const int lk   = blockIdx.y;
    const int k    = k0 + lk;
    const int lane = threadIdx.x & 63;
    const int wave = threadIdx.x >> 6;
    const int m16  = lane & 15;
    const int q    = lane >> 4;        // 0..3

    const ushort* wb = weightb + (size_t)k * C * C;
    bf16x8 xf[4][2];
    #pragma unroll
    for (int nt = 0; nt < 4; ++nt)
        #pragma unroll
        for (int kc = 0; kc < 2; ++kc)
            #pragma unroll
            for (int j = 0; j < 8; ++j)
                xf[nt][kc][j] = (short)wb[(size_t)(kc * 32 + 8 * q + j) * C + nt * 16 + m16];

    ushort* Pk = P + (size_t)lk * NIN * C;
    const int tiles = NIN / 16;        // 6250 exactly

    for (int tile = blockIdx.x * 4 + wave; tile < tiles; tile += gridDim.x * 4) {
        const int mbase = tile * 16;
        const ushort* fr = featsb + (size_t)(mbase + m16) * C;
        bf16x8 y0 = *reinterpret_cast<const bf16x8*>(fr + 8 * q);
        bf16x8 y1 = *reinterpret_cast<const bf16x8*>(fr + 32 + 8 * q);

        f32x4 acc0 = {0,0,0,0}, acc1 = {0,0,0,0}, acc2 = {0,0,0,0}, acc3 = {0,0,0,0};
        acc0 = __builtin_amdgcn_mfma_f32_16x16x32_bf16(xf[0][0], y0, acc0, 0, 0, 0);
        acc1 = __builtin_amdgcn_mfma_f32_16x16x32_bf16(xf[1][0], y0, acc1, 0, 0, 0);
        acc2 = __builtin_amdgcn_mfma_f32_16x16x32_bf16(xf[2][0], y0, acc2, 0, 0, 0);
        acc3 = __builtin_amdgcn_mfma_f32_16x16x32_bf16(xf[3][0], y0, acc3, 0, 0, 0);
        acc0 = __builtin_amdgcn_mfma_f32_16x16x32_bf16(xf[0][1], y1, acc0, 0, 0, 0);
        acc1 = __builtin_amdgcn_mfma_f32_16x16x32_bf16(xf[1][1], y1, acc1, 0, 0, 0);
        acc2 = __builtin_amdgcn_mfma_f32_16x16x32_bf16(xf[2][1], y1, acc2, 0, 0, 0);
        acc3 = __builtin_amdgcn_mfma_f32_16x16x32_bf16(xf[3][1], y1, acc3, 0, 0, 0);

        ushort* prow = Pk + (size_t)(mbase + m16) * C;
        f32x4 accs[4] = {acc0, acc1, acc2, acc3};
        #pragma unroll
        for (int nt = 0; nt < 4; ++nt) {
            union { ushort u[4]; uint2 v; } pk;
            #pragma unroll
            for (int r = 0; r < 4; ++r) {
                __hip_bfloat16 h = __float2bfloat16(accs[nt][r]);
                pk.u[r] = *reinterpret_cast<ushort*>(&h);
            }
            *reinterpret_cast<uint2*>(prow + nt * 16 + q * 4) = pk.v;
        }
    }
}

// ---------------- Phase B: bucket binning (fixed-capacity segments) --------
// Segment (g,b) at binned[(g*NBUK+b)*CAP .. +CAP): pairs whose out_idx is in
// rows [b*256, b*256+256) for group g. Count kernel and scan are eliminated;
// gcur[g*NBUK+b] is both the reservation cursor and the final count.
// Payload: bits[0,17)=ii  bits[17,21)=lk (group-local k)  bits[21,29)=oi&255.

__global__ __launch_bounds__(256)
void bin_fill_kernel(const int* __restrict__ in_idx, const int* __restrict__ out_idx,
                     int* __restrict__ gcur, uint32_t* __restrict__ binned,
                     int kpg)
{
    __shared__ int hist[NBUK];
    __shared__ int base[NBUK];
    const int g    = blockIdx.y;
    const int kbeg = g * kpg;
    const int tbeg = kbeg * NIN;
    int tend = (g + 1) * kpg * NIN;
    if (tend > NPAIR) tend = NPAIR;

    for (int i = threadIdx.x; i < NBUK; i += 256) hist[i] = 0;
    __syncthreads();
    const int t0 = tbeg + blockIdx.x * IPB_F;
    #pragma unroll 4
    for (int j = 0; j < IPB_F / 256; ++j) {
        int t = t0 + j * 256 + threadIdx.x;
        if (t < tend) atomicAdd(&hist[out_idx[t] >> 8], 1);
    }
    __syncthreads();
    int* gc = gcur + (size_t)g * NBUK;
    for (int i = threadIdx.x; i < NBUK; i += 256) {
        int c = hist[i];
        base[i] = c ? atomicAdd(&gc[i], c) : 0;
    }
    __syncthreads();
    #pragma unroll 4
    for (int j = 0; j < IPB_F / 256; ++j) {
        int t = t0 + j * 256 + threadIdx.x;
        if (t < tend) {
            int k   = t / NIN;
            int oi  = out_idx[t];
            int ii  = in_idx[t];
            int bkt = oi >> 8;
            int p   = atomicSub(&hist[bkt], 1) - 1;
            int pos = base[bkt] + p;
            if (pos < CAP) {   // 11-sigma guard against segment overflow
                uint32_t payload = ((uint32_t)(oi & 255) << 21)
                                 | ((uint32_t)(k - kbeg) << 17)
                                 | (uint32_t)ii;
                binned[((size_t)g * NBUK + bkt) * CAP + pos] = payload;
            }
        }
    }
}

// ---------------- Phase C: per-half-bucket LDS sort + gather + BN/ReLU -----
// Block = (bucket b, half sub): 128 output rows. Counting-sort the segment's
// payloads that land in this half, then 16 threads/row reduce P rows with
// 4-deep load ILP.
__global__ __launch_bounds__(256)
void gather_bucket_kernel(const uint2* __restrict__ P2,
                          const uint32_t* __restrict__ binned,
                          const int* __restrict__ gcur, int gbase,
                          const float* __restrict__ gamma,
                          const float* __restrict__ beta,
                          const float* __restrict__ mean,
                          const float* __restrict__ var,
                          float* __restrict__ out,
                          int accumulate, int finalize)
{
    __shared__ uint32_t sIt[SIT];
    __shared__ int sCnt[RPB];
    __shared__ int sOff[RPB + 1];
    __shared__ int sCur[RPB];

    const int b   = blockIdx.x;
    const int sub = blockIdx.y;                  // 0/1 -> rows [sub*128, +128)
    const int t   = threadIdx.x;
    const size_t beg = (size_t)(gbase + b) * CAP;
    int n = gcur[gbase + b];
    if (n > CAP) n = CAP;
    const int rlo = sub * RPB;

    if (t < RPB) sCnt[t] = 0;
    __syncthreads();
    for (int i = t; i < n; i += 256) {
        int rl = (int)(binned[beg + i] >> 21) - rlo;
        if ((unsigned)rl < (unsigned)RPB) atomicAdd(&sCnt[rl], 1);
    }
    __syncthreads();
    // inclusive scan over RPB entries (first 128 threads)
    if (t < RPB) sOff[t + 1] = sCnt[t];
    __syncthreads();
    for (int off = 1; off < RPB; off <<= 1) {
        int x = 0;
        if (t < RPB && t >= off) x = sOff[t + 1 - off];
        __syncthreads();
        if (t < RPB) sOff[t + 1] += x;
        __syncthreads();
    }
    if (t == 0) sOff[0] = 0;
    __syncthreads();
    if (t < RPB) sCur[t] = sOff[t + 1] - sCnt[t];
    __syncthreads();
    for (int i = t; i < n; i += 256) {
        uint32_t pl = binned[beg + i];
        int rl = (int)(pl >> 21) - rlo;
        if ((unsigned)rl < (unsigned)RPB) {
            int slot = atomicAdd(&sCur[rl], 1);
            if (slot < SIT) sIt[slot] = pl;
        }
    }
    __syncthreads();

    const int cp = t & 15;
    const int c0 = cp * 4;
    float sc[4], sh[4];
    if (finalize) {
        #pragma unroll
        for (int r = 0; r < 4; ++r) {
            const int c = c0 + r;
            float s = gamma[c] * rsqrtf(var[c] + EPS);
            sc[r] = s;
            sh[r] = beta[c] - mean[c] * s;
        }
    }

    float4* out4 = reinterpret_cast<float4*>(out);
    #pragma unroll 1
    for (int it = 0; it < RPB / 16; ++it) {
        const int rl  = (t >> 4) + it * 16;
        const int row = b * 256 + rlo + rl;
        if (row >= NOUT) continue;
        int j  = sOff[rl];
        const int je = sOff[rl + 1];

        float a0 = 0.f, a1 = 0.f, a2 = 0.f, a3 = 0.f;
        for (; j + 3 < je; j += 4) {              // 4 loads in flight
            uint32_t p0 = sIt[j],     p1 = sIt[j + 1];
            uint32_t p2 = sIt[j + 2], p3 = sIt[j + 3];
            uint2 u0 = P2[((size_t)((p0 >> 17) & 15) * NIN + (p0 & 0x1FFFF)) * 16 + cp];
            uint2 u1 = P2[((size_t)((p1 >> 17) & 15) * NIN + (p1 & 0x1FFFF)) * 16 + cp];
            uint2 u2 = P2[((size_t)((p2 >> 17) & 15) * NIN + (p2 & 0x1FFFF)) * 16 + cp];
            uint2 u3 = P2[((size_t)((p3 >> 17) & 15) * NIN + (p3 & 0x1FFFF)) * 16 + cp];
            a0 += __uint_as_float(u0.x << 16);
            a1 += __uint_as_float(u0.x & 0xffff0000u);
            a2 += __uint_as_float(u0.y << 16);
            a3 += __uint_as_float(u0.y & 0xffff0000u);
            a0 += __uint_as_float(u1.x << 16);
            a1 += __uint_as_float(u1.x & 0xffff0000u);
            a2 += __uint_as_float(u1.y << 16);
            a3 += __uint_as_float(u1.y & 0xffff0000u);
            a0 += __uint_as_float(u2.x << 16);
            a1 += __uint_as_float(u2.x & 0xffff0000u);
            a2 += __uint_as_float(u2.y << 16);
            a3 += __uint_as_float(u2.y & 0xffff0000u);
            a0 += __uint_as_float(u3.x << 16);
            a1 += __uint_as_float(u3.x & 0xffff0000u);
            a2 += __uint_as_float(u3.y << 16);
            a3 += __uint_as_float(u3.y & 0xffff0000u);
        }
        for (; j < je; ++j) {
            uint32_t p0 = sIt[j];
            uint2 u0 = P2[((size_t)((p0 >> 17) & 15) * NIN + (p0 & 0x1FFFF)) * 16 + cp];
            a0 += __uint_as_float(u0.x << 16);
            a1 += __uint_as_float(u0.x & 0xffff0000u);
            a2 += __uint_as_float(u0.y << 16);
            a3 += __uint_as_float(u0.y & 0xffff0000u);
        }

        const size_t oidx = (size_t)row * 16 + cp;
        if (accumulate) {
            float4 pv = out4[oidx];
            a0 += pv.x; a1 += pv.y; a2 += pv.z; a3 += pv.w;
        }
        if (finalize) {
            a0 = fmaf(a0, sc[0], sh[0]); a0 = a0 > 0.f ? a0 : 0.f;
            a1 = fmaf(a1, sc[1], sh[1]); a1 = a1 > 0.f ? a1 : 0.f;
            a2 = fmaf(a2, sc[2], sh[2]); a2 = a2 > 0.f ? a2 : 0.f;
            a3 = fmaf(a3, sc[3], sh[3]); a3 = a3 > 0.f ? a3 : 0.f;
        }
        out4[oidx] = make_float4(a0, a1, a2, a3);
    }
}

// ---------------- Fallback (atomic path, tiny ws) --------------------------
__global__ __launch_bounds__(256)
void conv_scatter_kernel(const float* __restrict__ feats,
                         const float* __restrict__ weight,
                         const int*   __restrict__ in_idx,
                         const int*   __restrict__ out_idx,
                         float*       __restrict__ out)
{
    const int k    = blockIdx.y;
    const int lane = threadIdx.x & 63;
    const int wave = threadIdx.x >> 6;
    const int wavesInGrid = gridDim.x * 4;
    const int waveId      = blockIdx.x * 4 + wave;

    const float* wk = weight + (size_t)k * C * C + lane;
    float w[C];
    #pragma unroll
    for (int ci = 0; ci < C; ++ci) w[ci] = wk[(size_t)ci * C];

    const int* ii_k = in_idx  + (size_t)k * NIN;
    const int* oi_k = out_idx + (size_t)k * NIN;

    for (int r = waveId; r < NIN; r += wavesInGrid) {
        const int ii = ii_k[r];
        const int oi = oi_k[r];
        const float4* frow = reinterpret_cast<const float4*>(feats + (size_t)ii * C);
        float acc = 0.0f;
        #pragma unroll
        for (int j = 0; j < C / 4; ++j) {
            float4 f = frow[j];
            acc = fmaf(f.x, w[4 * j + 0], acc);
            acc = fmaf(f.y, w[4 * j + 1], acc);
            acc = fmaf(f.z, w[4 * j + 2], acc);
            acc = fmaf(f.w, w[4 * j + 3], acc);
        }
        atomicAdd(out + (size_t)oi * C + lane, acc);
    }
}

__global__ __launch_bounds__(256)
void bn_relu_kernel(float* __restrict__ out,
                    const float* __restrict__ gamma,
                    const float* __restrict__ beta,
                    const float* __restrict__ mean,
                    const float* __restrict__ var)
{
    const int total4 = NOUT * C / 4;
    int idx = blockIdx.x * blockDim.x + threadIdx.x;
    if (idx >= total4) return;
    const int c0 = (idx * 4) & (C - 1);
    float sc[4], sh[4];
    #pragma unroll
    for (int j = 0; j < 4; ++j) {
        const int c  = c0 + j;
        const float s = gamma[c] * rsqrtf(var[c] + EPS);
        sc[j] = s;
        sh[j] = beta[c] - mean[c] * s;
    }
    float4* p = reinterpret_cast<float4*>(out) + idx;
    float4 v = *p;
    v.x = fmaf(v.x, sc[0], sh[0]); v.x = v.x > 0.f ? v.x : 0.f;
    v.y = fmaf(v.y, sc[1], sh[1]); v.y = v.y > 0.f ? v.y : 0.f;
    v.z = fmaf(v.z, sc[2], sh[2]); v.z = v.z > 0.f ? v.z : 0.f;
    v.w = fmaf(v.w, sc[3], sh[3]); v.w = v.w > 0.f ? v.w : 0.f;
    *p = v;
}

// ---------------------------------------------------------------------------
extern "C" void kernel_launch(void* const* d_in, const int* in_sizes, int n_in,
                              void* d_out, int out_size, void* d_ws, size_t ws_size,
                              hipStream_t stream) {
    const float* feats   = (const float*)d_in[0];
    const float* weight  = (const float*)d_in[1];
    const int*   in_idx  = (const int*)  d_in[2];
    const int*   out_idx = (const int*)  d_in[3];
    const float* gamma   = (const float*)d_in[4];
    const float* beta    = (const float*)d_in[5];
    const float* rmean   = (const float*)d_in[6];
    const float* rvar    = (const float*)d_in[7];
    float* out = (float*)d_out;

    auto align = [](size_t x) { return (x + 255) & ~(size_t)255; };

    // kpg=9 (G=3): P chunk 115 MB stays L3-resident for the gemm write /
    // gather read; one fewer out-RMW pass than G=4 (round-8/9 comparison).
    int kpg = 0, G = 0;
    size_t oBin = 0, oGc = 0, oFb = 0, oWb = 0, oP = 0;
    for (int t = 9; t >= 1; --t) {
        int g  = (KOFF + t - 1) / t;
        int gb = g * NBUK;
        size_t a = 0;
        size_t bi = a; a += align((size_t)gb * CAP * 4);          // binned segments
        size_t gc = a; a += align((size_t)gb * 4);                // gcur (cursor+count)
        size_t fb = a; a += align((size_t)NIN * C * 2);           // feats bf16
        size_t wb = a; a += align((size_t)KOFF * C * C * 2);      // weight bf16
        size_t q_ = a; a += align((size_t)t * NIN * C * 2);       // P_chunk bf16
        if (a <= ws_size) {
            kpg = t; G = g;
            oBin = bi; oGc = gc; oFb = fb; oWb = wb; oP = q_;
            break;
        }
    }

    if (kpg == 0) {
        hipMemsetAsync(out, 0, (size_t)out_size * sizeof(float), stream);
        dim3 grid(512, KOFF);
        conv_scatter_kernel<<<grid, 256, 0, stream>>>(feats, weight, in_idx, out_idx, out);
        const int total4 = NOUT * C / 4;
        bn_relu_kernel<<<(total4 + 255) / 256, 256, 0, stream>>>(out, gamma, beta, rmean, rvar);
        return;
    }

    const int GB = G * NBUK;
    char* ws = (char*)d_ws;
    uint32_t* binned = (uint32_t*)(ws + oBin);
    int* gcur = (int*)(ws + oGc);
    ushort* featsb  = (ushort*)(ws + oFb);
    ushort* weightb = (ushort*)(ws + oWb);
    ushort* P       = (ushort*)(ws + oP);

    // --- bf16 conversions ---
    {
        int n8f = NIN * C / 8;
        cvt_bf16_kernel<<<(n8f + 255) / 256, 256, 0, stream>>>(feats, featsb, n8f);
        int n8w = KOFF * C * C / 8;
        cvt_bf16_kernel<<<(n8w + 255) / 256, 256, 0, stream>>>(weight, weightb, n8w);
    }

    // --- Bucket binning (single fill pass, fixed-capacity segments) ---
    hipMemsetAsync(gcur, 0, (size_t)GB * sizeof(int), stream);
    {
        int itemsPerGroup = kpg * NIN;
        int nbF = (itemsPerGroup + IPB_F - 1) / IPB_F;
        dim3 gF(nbF, G);
        bin_fill_kernel<<<gF, 256, 0, stream>>>(in_idx, out_idx, gcur, binned, kpg);
    }

    // --- Per-group: MFMA GEMM chunk, then half-bucket gather into out ---
    for (int g = 0; g < G; ++g) {
        const int k0   = g * kpg;
        const int kcnt = (k0 + kpg <= KOFF) ? kpg : (KOFF - k0);

        dim3 grid(128, kcnt);
        gemm_mfma_kernel<<<grid, 256, 0, stream>>>(featsb, weightb, P, k0);

        dim3 ggrid(NBUK, 2);
        gather_bucket_kernel<<<ggrid, 256, 0, stream>>>(
            (const uint2*)P, binned, gcur, g * NBUK,
            gamma, beta, rmean, rvar, out,
            /*accumulate=*/(g > 0), /*finalize=*/(g == G - 1));
    }
}